// Round 19
// baseline (83.046 us; speedup 1.0000x reference)
//
#include <hip/hip_runtime.h>
#include <hip/hip_fp16.h>

typedef _Float16 f16;
typedef _Float16 half4 __attribute__((ext_vector_type(4)));
typedef _Float16 half8 __attribute__((ext_vector_type(8)));
typedef float f32x4 __attribute__((ext_vector_type(4)));

#define BATCH 8
#define NTOK 2048
#define FIN 256
#define FOUT 256
#define ALPHA 0.2f
#define LOG2E 1.44269504088896340736f

// WhT swizzled layout: [b][slab(32)][o(256)][u(8)][q(8)] f16; logical
// Wh[n][o] (n = slab*64 + jg8*8 + jq) lives at u = jg8 ^ (o & 7).
// Each slab is a contiguous 32 KB block == its LDS image in k_attn.

__device__ __forceinline__ void gload16(const void* g, void* l) {
    __builtin_amdgcn_global_load_lds(
        (const __attribute__((address_space(1))) unsigned int*)(g),
        (__attribute__((address_space(3))) unsigned int*)(l), 16, 0, 0);
}

// ---------------- K0: W[k][o] fp32 -> WT[o][k] fp16 ----------------
__global__ void k_wt(const float* __restrict__ W, f16* __restrict__ WT) {
    __shared__ float t[32][33];
    int o0 = blockIdx.x * 32, k0 = blockIdx.y * 32;
    int tx = threadIdx.x, ty = threadIdx.y;
    t[ty][tx] = W[(k0 + ty) * FOUT + o0 + tx];
    __syncthreads();
    WT[(o0 + ty) * FIN + (k0 + tx)] = (f16)t[tx][ty];
}

// ---------------- K1: gemm -> swizzled WhT slab + fused s1/s2 epilogue ----------------
__global__ __launch_bounds__(256) void k_gemm(const float* __restrict__ x,
                                              const f16* __restrict__ WT,
                                              const float* __restrict__ a,
                                              f16* __restrict__ WhT,
                                              float* __restrict__ s1,
                                              float* __restrict__ s2) {
    __shared__ __align__(16) char gsmem[46080];
    int t = threadIdx.x;
    int lane = t & 63, w = t >> 6;
    f16* Ah = (f16*)gsmem;               // [64][72]
    f16* Bt = (f16*)(gsmem + 9216);      // [256][72]
    int m0 = blockIdx.x * 64;
    int lr = lane & 15, lg = lane >> 4;
    f32x4 acc[4][4] = {};

    for (int k0 = 0; k0 < FIN; k0 += 64) {
        {
            int r = t >> 2, c = (t & 3) * 16;
            const float* src = x + (size_t)(m0 + r) * FIN + k0 + c;
            f32x4 v0 = *(const f32x4*)(src);
            f32x4 v1 = *(const f32x4*)(src + 4);
            f32x4 v2 = *(const f32x4*)(src + 8);
            f32x4 v3 = *(const f32x4*)(src + 12);
            half8 h0, h1;
#pragma unroll
            for (int q = 0; q < 4; q++) {
                h0[q] = (f16)v0[q]; h0[q + 4] = (f16)v1[q];
                h1[q] = (f16)v2[q]; h1[q + 4] = (f16)v3[q];
            }
            f16* dst = Ah + r * 72 + c;
            *(half8*)dst = h0;
            *(half8*)(dst + 8) = h1;
        }
        {
            const f16* src = WT + (size_t)t * FIN + k0;
            f16* dst = Bt + t * 72;
#pragma unroll
            for (int q = 0; q < 8; q++)
                *(half8*)(dst + q * 8) = *(const half8*)(src + q * 8);
        }
        __syncthreads();
#pragma unroll
        for (int kc = 0; kc < 2; kc++) {
            int krow = kc * 32 + lg * 8;
            half8 af[4], bf[4];
#pragma unroll
            for (int fi = 0; fi < 4; fi++)
                af[fi] = *(half8*)(Ah + (fi * 16 + lr) * 72 + krow);
#pragma unroll
            for (int fo = 0; fo < 4; fo++)
                bf[fo] = *(half8*)(Bt + (w * 64 + fo * 16 + lr) * 72 + krow);
#pragma unroll
            for (int fi = 0; fi < 4; fi++)
#pragma unroll
                for (int fo = 0; fo < 4; fo++)
                    acc[fi][fo] = __builtin_amdgcn_mfma_f32_16x16x32_f16(
                        af[fi], bf[fo], acc[fi][fo], 0, 0, 0);
        }
        __syncthreads();
    }

    int b = m0 >> 11;
    int slab_i = (m0 & (NTOK - 1)) >> 6;
    int nbase = m0 & (NTOK - 1);

    float* sred = (float*)gsmem;          // aliases Ah
    f16* slab = (f16*)(gsmem + 9216);     // 32 KB slab image (aliases Bt)
    float a1v[4], a2v[4];
#pragma unroll
    for (int fo = 0; fo < 4; fo++) {
        int o = w * 64 + fo * 16 + lr;
        a1v[fo] = a[o];
        a2v[fo] = a[FOUT + o];
    }
#pragma unroll
    for (int fi = 0; fi < 4; fi++) {
        f32x4 p1 = {}, p2 = {};
#pragma unroll
        for (int fo = 0; fo < 4; fo++) {
            p1 += acc[fi][fo] * a1v[fo];
            p2 += acc[fi][fo] * a2v[fo];
        }
#pragma unroll
        for (int q = 0; q < 4; q++) {
#pragma unroll
            for (int d = 1; d < 16; d <<= 1) {
                p1[q] += __shfl_xor(p1[q], d);
                p2[q] += __shfl_xor(p2[q], d);
            }
        }
        if (lr == 0) {
            int row = fi * 16 + lg * 4;
#pragma unroll
            for (int q = 0; q < 4; q++) {
                sred[w * 64 + row + q] = p1[q];
                sred[256 + w * 64 + row + q] = p2[q];
            }
        }
    }
#pragma unroll
    for (int fi = 0; fi < 4; fi++) {
        int jg8 = fi * 2 + (lg >> 1), jq0 = (lg & 1) * 4;
#pragma unroll
        for (int fo = 0; fo < 4; fo++) {
            int o = w * 64 + fo * 16 + lr;
            half4 hv;
#pragma unroll
            for (int q = 0; q < 4; q++) hv[q] = (f16)acc[fi][fo][q];
            *(half4*)(slab + o * 64 + ((jg8 ^ (o & 7)) * 8) + jq0) = hv;
        }
    }
    __syncthreads();

    if (t < 64) {
        s1[(size_t)b * NTOK + nbase + t] =
            sred[t] + sred[64 + t] + sred[128 + t] + sred[192 + t];
    } else if (t < 128) {
        int r2 = t - 64;
        s2[(size_t)b * NTOK + nbase + r2] =
            sred[256 + r2] + sred[320 + r2] + sred[384 + r2] + sred[448 + r2];
    }
    {
        const int4* sl = (const int4*)slab;
        int4* gd = (int4*)(WhT + ((size_t)(b * 32 + slab_i) * 256) * 64);
#pragma unroll
        for (int i = 0; i < 8; i++) gd[i * 256 + t] = sl[i * 256 + t];
    }
}

// ---------------- K3: self-packing fused attn, P-in-LDS-once ----------------
// 8 waves, 64 rows/block. Softmax role: wave w owns rows w*8..w*8+7 (lane =
// (row, j8-granule)), P computed ONCE into double-buffered XOR-swizzled LDS.
// Output role: wave = rg(2) x oq(4), disjoint (rows x o) -> no combine at all.
// exp2 path (s1/s2 pre-scaled by log2e). Slab DMA double-buffered; adj
// self-packed in prologue with 2-row-pair deep prefetch (256 B/lane).
__global__ __launch_bounds__(512, 1) void k_attn(const int* __restrict__ adj,
                                                 const f16* __restrict__ WhT,
                                                 const float* __restrict__ s1g,
                                                 const float* __restrict__ s2g,
                                                 float* __restrict__ out) {
    __shared__ __align__(16) char smem[107296];
    f16* Bl = (f16*)smem;                               // 2 x 32 KB WhT slabs
    float* s2_lds = (float*)(smem + 65536);             // [2048] (scaled)
    unsigned* mask_lds = (unsigned*)(smem + 73728);     // [64][66] u32
    f16* P_lds = (f16*)(smem + 90624);                  // 2 x [64][64] f16
    float* l_lds = (float*)(smem + 107008);             // [64]
    float* wmax = (float*)(smem + 107264);              // [8]

    int b = blockIdx.x & 7;                             // batch -> XCD pinning
    int i0 = (blockIdx.x >> 3) * 64;
    int t = threadIdx.x;
    int lane = t & 63, w = t >> 6;
    int lr = lane & 15, lg = lane >> 4;
    int oq = w & 3, rg = w >> 2;
    int r4 = lane >> 3, j8 = lane & 7;
    int srow = w * 8 + r4;                              // softmax-role row

    {   // s2 -> LDS (scaled by log2e) + block max
        f32x4 sv4 = ((const f32x4*)(s2g + (size_t)b * NTOK))[t];
        sv4 = sv4 * LOG2E;
        ((f32x4*)s2_lds)[t] = sv4;
        float tmx = fmaxf(fmaxf(sv4[0], sv4[1]), fmaxf(sv4[2], sv4[3]));
#pragma unroll
        for (int d = 1; d < 64; d <<= 1) tmx = fmaxf(tmx, __shfl_xor(tmx, d));
        if (lane == 0) wmax[w] = tmx;
    }

    const char* wsrc = (const char*)WhT + (size_t)b * (32 * 32768);
    {   // slabs 0 and 1 DMA -> buf 0, buf 1
        const char* s0 = wsrc + w * 4096 + lane * 16;
        char* d0 = (char*)Bl + w * 4096;
#pragma unroll
        for (int k = 0; k < 4; k++) gload16(s0 + k * 1024, d0 + k * 1024);
        const char* s1p = wsrc + 32768 + w * 4096 + lane * 16;
        char* d1 = (char*)Bl + 32768 + w * 4096;
#pragma unroll
        for (int k = 0; k < 4; k++) gload16(s1p + k * 1024, d1 + k * 1024);
    }

    {   // adj self-pack: wave w -> rows w*8..+7, row-contiguous, 2-row pairs
        const int4* abase = (const int4*)(adj + ((size_t)(b * NTOK + i0 + w * 8)) * NTOK)
                            + lane * 8;
        int4 c0[8], c1[8];
#pragma unroll
        for (int k = 0; k < 8; k++) { c0[k] = abase[k]; c1[k] = abase[512 + k]; }
        for (int rp = 0; rp < 4; rp++) {
            int4 n0[8], n1[8];
            if (rp < 3) {
#pragma unroll
                for (int k = 0; k < 8; k++) {
                    n0[k] = abase[(2 * rp + 2) * 512 + k];
                    n1[k] = abase[(2 * rp + 3) * 512 + k];
                }
            }
            unsigned m0 = 0, m1 = 0;
#pragma unroll
            for (int k = 0; k < 8; k++) {
                m0 |= (unsigned)(c0[k].x > 0) << (k * 4);
                m0 |= (unsigned)(c0[k].y > 0) << (k * 4 + 1);
                m0 |= (unsigned)(c0[k].z > 0) << (k * 4 + 2);
                m0 |= (unsigned)(c0[k].w > 0) << (k * 4 + 3);
                m1 |= (unsigned)(c1[k].x > 0) << (k * 4);
                m1 |= (unsigned)(c1[k].y > 0) << (k * 4 + 1);
                m1 |= (unsigned)(c1[k].z > 0) << (k * 4 + 2);
                m1 |= (unsigned)(c1[k].w > 0) << (k * 4 + 3);
            }
            mask_lds[(w * 8 + 2 * rp) * 66 + lane] = m0;
            mask_lds[(w * 8 + 2 * rp + 1) * 66 + lane] = m1;
#pragma unroll
            for (int k = 0; k < 8; k++) { c0[k] = n0[k]; c1[k] = n1[k]; }
        }
    }

    float s1r = s1g[(size_t)b * NTOK + i0 + srow] * LOG2E;
    float l_acc = 0.f;

    __syncthreads();                                    // everything staged

    float s2m = wmax[0];
#pragma unroll
    for (int k = 1; k < 8; k++) s2m = fmaxf(s2m, wmax[k]);
    float txr = s1r + s2m;
    float mxr = fmaxf(txr, ALPHA * txr);                // fixed shift (scaled)

    f32x4 acc[2][4] = {};                               // [fi][ot]

    for (int s = 0; s < 32; s++) {
        int buf = s & 1;
        {   // phase A: softmax for step s (each lane: 8 elements of its row)
            unsigned mw = mask_lds[srow * 66 + s * 2 + (j8 >> 2)];
            unsigned bits = (mw >> ((j8 & 3) * 8)) & 0xffu;
            f32x4 sA = *(const f32x4*)&s2_lds[s * 64 + j8 * 8];
            f32x4 sB = *(const f32x4*)&s2_lds[s * 64 + j8 * 8 + 4];
            half8 ph;
#pragma unroll
            for (int q = 0; q < 8; q++) {
                float sv = q < 4 ? sA[q] : sB[q - 4];
                float sx = s1r + sv;
                float ev = fmaxf(sx, ALPHA * sx);
                float p = ((bits >> q) & 1) ? exp2f(ev - mxr) : 0.f;
                l_acc += p;
                ph[q] = (f16)p;
            }
            *(half8*)&P_lds[buf * 4096 + srow * 64 + ((j8 ^ (srow & 7)) * 8)] = ph;
        }
        __syncthreads();                                // P(s) ready; DMA drained

        {   // phase B: MFMA for step s
            const f16* Pb = P_lds + buf * 4096;
            const f16* Bb = Bl + buf * 16384;
            half8 af[2][2];
#pragma unroll
            for (int fi = 0; fi < 2; fi++)
#pragma unroll
                for (int kc = 0; kc < 2; kc++) {
                    int ra = rg * 32 + fi * 16 + lr;
                    af[fi][kc] = *(const half8*)&Pb[ra * 64 + (((kc * 4 + lg) ^ (ra & 7)) * 8)];
                }
#pragma unroll
            for (int ot = 0; ot < 4; ot++) {
                int o = oq * 64 + ot * 16 + lr;
#pragma unroll
                for (int kc = 0; kc < 2; kc++) {
                    half8 bf = *(const half8*)&Bb[o * 64 + (((kc * 4 + lg) ^ (o & 7)) * 8)];
                    acc[0][ot] = __builtin_amdgcn_mfma_f32_16x16x32_f16(af[0][kc], bf, acc[0][ot], 0, 0, 0);
                    acc[1][ot] = __builtin_amdgcn_mfma_f32_16x16x32_f16(af[1][kc], bf, acc[1][ot], 0, 0, 0);
                }
            }
        }
        __syncthreads();                                // Bl[buf] reads done

        if (s < 30) {                                   // issue slab s+2 -> buf
            const char* src = wsrc + (size_t)(s + 2) * 32768 + w * 4096 + lane * 16;
            char* dst = (char*)Bl + buf * 32768 + w * 4096;
#pragma unroll
            for (int k = 0; k < 4; k++) gload16(src + k * 1024, dst + k * 1024);
        }
    }

    // l: reduce over the 8 j8-lanes of each row
    l_acc += __shfl_xor(l_acc, 1);
    l_acc += __shfl_xor(l_acc, 2);
    l_acc += __shfl_xor(l_acc, 4);
    if (j8 == 0) l_lds[srow] = l_acc;
    __syncthreads();

    // epilogue: divide + ELU + store (wave owns disjoint rows x o)
    f32x4 rl0, rl1;
#pragma unroll
    for (int q = 0; q < 4; q++) {
        rl0[q] = 1.f / l_lds[rg * 32 + lg * 4 + q];
        rl1[q] = 1.f / l_lds[rg * 32 + 16 + lg * 4 + q];
    }
#pragma unroll
    for (int ot = 0; ot < 4; ot++) {
        int o = oq * 64 + ot * 16 + lr;
#pragma unroll
        for (int q = 0; q < 4; q++) {
            int ra = rg * 32 + lg * 4 + q;
            float u = acc[0][ot][q] * rl0[q];
            u = u > 0.f ? u : __expf(u) - 1.f;
            __builtin_nontemporal_store(u, &out[((size_t)(b * NTOK + i0 + ra)) * FOUT + o]);
            int rb = ra + 16;
            float v = acc[1][ot][q] * rl1[q];
            v = v > 0.f ? v : __expf(v) - 1.f;
            __builtin_nontemporal_store(v, &out[((size_t)(b * NTOK + i0 + rb)) * FOUT + o]);
        }
    }
}

extern "C" void kernel_launch(void* const* d_in, const int* in_sizes, int n_in,
                              void* d_out, int out_size, void* d_ws, size_t ws_size,
                              hipStream_t stream) {
    const float* x = (const float*)d_in[0];
    const int* adj = (const int*)d_in[1];
    const float* W = (const float*)d_in[2];
    const float* a = (const float*)d_in[3];
    float* out = (float*)d_out;

    char* ws = (char*)d_ws;
    f16* WT = (f16*)ws;                                     // 128 KB
    f16* WhT = (f16*)(ws + 131072);                         // 8 MB swizzled
    float* s1 = (float*)(ws + 131072 + 8388608);            // 64 KB
    float* s2 = s1 + BATCH * NTOK;                          // 64 KB

    k_wt<<<dim3(FOUT / 32, FIN / 32), dim3(32, 32), 0, stream>>>(W, WT);
    k_gemm<<<dim3(BATCH * NTOK / 64), 256, 0, stream>>>(x, WT, a, WhT, s1, s2);
    k_attn<<<dim3(BATCH * NTOK / 64), 512, 0, stream>>>(adj, WhT, s1, s2, out);
}